// Round 1
// baseline (203.947 us; speedup 1.0000x reference)
//
#include <hip/hip_runtime.h>
#include <math.h>

#define NN  8192
#define DIM 128
#define NE  262144
#define XB  128   // partial blocks for X̂ᵀX

// ---------------------------------------------------------------- K1: row prep
// one wave (64 lanes) per row, 4 rows per 256-thread block
__global__ __launch_bounds__(256) void k_row_prep(const float* __restrict__ x,
    float* __restrict__ rinv, int* __restrict__ deg, int* __restrict__ wcnt) {
  int tid  = threadIdx.x;
  int wave = tid >> 6, lane = tid & 63;
  int row  = blockIdx.x * 4 + wave;
  const float2* x2 = (const float2*)(x + (size_t)row * DIM);
  float2 v = x2[lane];
  float ss = v.x * v.x + v.y * v.y;
  #pragma unroll
  for (int m = 32; m > 0; m >>= 1) ss += __shfl_xor(ss, m);
  if (lane == 0) {
    rinv[row] = 1.0f / sqrtf(ss);
    deg[row]  = 1;          // self-loop
    wcnt[row] = 0;
  }
}

// ---------------------------------------------------- K2: M = X̂ᵀ X  (partials)
// 128 blocks x 256 threads; thread (ty,tx) owns an 8x8 tile of the 128x128 M
__global__ __launch_bounds__(256) void k_xtx_partial(const float* __restrict__ x,
    const float* __restrict__ rinv, float* __restrict__ Mpart) {
  __shared__ float xs[DIM];
  int tid = threadIdx.x;
  int ty = tid >> 4, tx = tid & 15;
  float acc[8][8];
  #pragma unroll
  for (int i = 0; i < 8; ++i)
    #pragma unroll
    for (int j = 0; j < 8; ++j) acc[i][j] = 0.f;

  int row0 = blockIdx.x * (NN / XB);
  for (int r = 0; r < NN / XB; ++r) {
    int row = row0 + r;
    if (tid < DIM) xs[tid] = x[(size_t)row * DIM + tid];
    __syncthreads();
    float rv = rinv[row];            // uniform -> scalar load
    float xa[8], xb[8];
    #pragma unroll
    for (int j = 0; j < 8; ++j) { xa[j] = xs[ty * 8 + j] * rv; xb[j] = xs[tx * 8 + j]; }
    #pragma unroll
    for (int i = 0; i < 8; ++i)
      #pragma unroll
      for (int j = 0; j < 8; ++j) acc[i][j] += xa[i] * xb[j];
    __syncthreads();
  }
  float* o = Mpart + (size_t)blockIdx.x * (DIM * DIM);
  #pragma unroll
  for (int i = 0; i < 8; ++i)
    #pragma unroll
    for (int j = 0; j < 8; ++j)
      o[(ty * 8 + i) * DIM + tx * 8 + j] = acc[i][j];
}

__global__ void k_xtx_reduce(const float* __restrict__ Mpart, float* __restrict__ M) {
  int j = blockIdx.x * blockDim.x + threadIdx.x;   // 16384 total
  float s = 0.f;
  for (int k = 0; k < XB; ++k) s += Mpart[(size_t)k * (DIM * DIM) + j];
  M[j] = s;
}

// ------------------------------------------------------------- K3: degree hist
__global__ void k_hist(const int* __restrict__ ei, int* __restrict__ deg) {
  int e = blockIdx.x * blockDim.x + threadIdx.x;
  atomicAdd(&deg[ei[NE + e]], 1);   // target = edge_index[1]
}

// -------------------------------------------------- K4: scan (1 block) + dis
__global__ __launch_bounds__(1024) void k_scan(const int* __restrict__ deg,
    int* __restrict__ offs, float* __restrict__ dis) {
  __shared__ int sums[1024];
  int t = threadIdx.x;
  int base_i = t * 8;
  int local[8];
  int s = 0;
  #pragma unroll
  for (int j = 0; j < 8; ++j) { int v = deg[base_i + j] - 1; local[j] = s; s += v; }
  sums[t] = s;
  __syncthreads();
  for (int off = 1; off < 1024; off <<= 1) {
    int v = (t >= off) ? sums[t - off] : 0;
    __syncthreads();
    sums[t] += v;
    __syncthreads();
  }
  int b = (t > 0) ? sums[t - 1] : 0;
  #pragma unroll
  for (int j = 0; j < 8; ++j) {
    offs[base_i + j] = b + local[j];
    dis[base_i + j]  = 1.0f / sqrtf((float)deg[base_i + j]);   // deg >= 1 always
  }
}

// -------------------------------------------------- K5: counting-sort placement
__global__ void k_place(const int* __restrict__ ei, const int* __restrict__ offs,
    int* __restrict__ wcnt, int* __restrict__ sorted) {
  int e = blockIdx.x * blockDim.x + threadIdx.x;
  int c = ei[NE + e];
  int p = offs[c] + atomicAdd(&wcnt[c], 1);
  sorted[p] = ei[e];                 // source = edge_index[0]
}

// -------------------------------- K6: xw = X@W  and  att = sigmoid(rinv*(X@M))
// W and M both LDS-resident (132 KB of gfx950's 160 KB). 256 blocks x 32 rows.
__global__ __launch_bounds__(256) void k_xw_att(const float* __restrict__ x,
    const float* __restrict__ W, const float* __restrict__ M,
    const float* __restrict__ rinv, float* __restrict__ xw, float* __restrict__ att) {
  __shared__ float Wl[DIM * DIM];
  __shared__ float Ml[DIM * DIM];
  __shared__ float xs[2][DIM];
  int tid = threadIdx.x;
  for (int i = tid; i < DIM * DIM; i += 256) { Wl[i] = W[i]; Ml[i] = M[i]; }
  __syncthreads();
  int sub = tid >> 7, col = tid & 127;
  int row_base = blockIdx.x * 32;
  for (int rp = 0; rp < 16; ++rp) {
    int r0 = row_base + rp * 2;
    xs[sub][col] = x[(size_t)(r0 + sub) * DIM + col];
    __syncthreads();
    int row = r0 + sub;
    float rv = rinv[row];
    float aw = 0.f, am = 0.f;
    #pragma unroll
    for (int a = 0; a < DIM; a += 4) {
      float4 xa = *(const float4*)&xs[sub][a];
      aw += xa.x * Wl[(a + 0) * DIM + col];
      am += xa.x * Ml[(a + 0) * DIM + col];
      aw += xa.y * Wl[(a + 1) * DIM + col];
      am += xa.y * Ml[(a + 1) * DIM + col];
      aw += xa.z * Wl[(a + 2) * DIM + col];
      am += xa.z * Ml[(a + 2) * DIM + col];
      aw += xa.w * Wl[(a + 3) * DIM + col];
      am += xa.w * Ml[(a + 3) * DIM + col];
    }
    xw[(size_t)row * DIM + col] = aw;
    float logit = am * rv;
    att[(size_t)row * DIM + col] = 1.0f / (1.0f + __expf(-logit));
    __syncthreads();
  }
}

// ---------------------------- K7: CSR gather + self-loop + bias + att-multiply
__global__ __launch_bounds__(128) void k_gather(const int* __restrict__ sorted,
    const int* __restrict__ offs, const int* __restrict__ deg,
    const float* __restrict__ dis, const float* __restrict__ xw,
    const float* __restrict__ att, const float* __restrict__ bias,
    float* __restrict__ out) {
  int c = blockIdx.x;
  int t = threadIdx.x;
  int base = offs[c];
  int cnt  = deg[c] - 1;
  float acc = 0.f;
  int k = 0;
  for (; k + 4 <= cnt; k += 4) {
    int s0 = sorted[base + k + 0];
    int s1 = sorted[base + k + 1];
    int s2 = sorted[base + k + 2];
    int s3 = sorted[base + k + 3];
    float d0 = dis[s0], d1 = dis[s1], d2 = dis[s2], d3 = dis[s3];
    acc += xw[(size_t)s0 * DIM + t] * d0;
    acc += xw[(size_t)s1 * DIM + t] * d1;
    acc += xw[(size_t)s2 * DIM + t] * d2;
    acc += xw[(size_t)s3 * DIM + t] * d3;
  }
  for (; k < cnt; ++k) {
    int s = sorted[base + k];
    acc += xw[(size_t)s * DIM + t] * dis[s];
  }
  float dc = dis[c];
  float g = acc * dc + xw[(size_t)c * DIM + t] * (dc * dc) + bias[t];
  out[(size_t)c * DIM + t] = g * att[(size_t)c * DIM + t];
}

// ---------------------------------------------------------------------- launch
extern "C" void kernel_launch(void* const* d_in, const int* in_sizes, int n_in,
                              void* d_out, int out_size, void* d_ws, size_t ws_size,
                              hipStream_t stream) {
  const float* x  = (const float*)d_in[0];   // [8192,128] f32
  const int*   ei = (const int*)  d_in[1];   // [2,262144] i32
  const float* W  = (const float*)d_in[2];   // [128,128] f32
  const float* b  = (const float*)d_in[3];   // [128] f32
  float* out = (float*)d_out;                // [8192,128] f32

  // ws layout (≈13.3 MB):
  float* xw     = (float*)d_ws;                    // N*DIM
  float* Mpart  = xw + (size_t)NN * DIM;           // XB*DIM*DIM (8 MB)
  float* att    = Mpart;                           // overlays Mpart AFTER reduce
  float* M      = Mpart + (size_t)XB * DIM * DIM;  // DIM*DIM
  float* rinv   = M + DIM * DIM;                   // N
  float* dis    = rinv + NN;                       // N
  int*   deg    = (int*)(dis + NN);                // N
  int*   wcnt   = deg + NN;                        // N
  int*   offs   = wcnt + NN;                       // N
  int*   sorted = offs + NN;                       // E

  k_row_prep  <<<NN / 4, 256, 0, stream>>>(x, rinv, deg, wcnt);
  k_xtx_partial<<<XB, 256, 0, stream>>>(x, rinv, Mpart);
  k_xtx_reduce<<<DIM * DIM / 256, 256, 0, stream>>>(Mpart, M);
  k_hist      <<<NE / 256, 256, 0, stream>>>(ei, deg);
  k_scan      <<<1, 1024, 0, stream>>>(deg, offs, dis);
  k_place     <<<NE / 256, 256, 0, stream>>>(ei, offs, wcnt, sorted);
  k_xw_att    <<<NN / 32, 256, 0, stream>>>(x, W, M, rinv, xw, att);
  k_gather    <<<NN, 128, 0, stream>>>(sorted, offs, deg, dis, xw, att, b, out);
}

// Round 2
// 150.873 us; speedup vs baseline: 1.3518x; 1.3518x over previous
//
#include <hip/hip_runtime.h>
#include <math.h>

#define NN  8192
#define DIM 128
#define NE  262144
#define XB  128   // partial blocks for X̂ᵀX (keeps ws layout identical to r1)

// ---------------------------------------------------------------- K1: row prep
__global__ __launch_bounds__(256) void k_row_prep(const float* __restrict__ x,
    float* __restrict__ rinv, int* __restrict__ deg, int* __restrict__ wcnt) {
  int tid  = threadIdx.x;
  int wave = tid >> 6, lane = tid & 63;
  int row  = blockIdx.x * 4 + wave;
  const float2* x2 = (const float2*)(x + (size_t)row * DIM);
  float2 v = x2[lane];
  float ss = v.x * v.x + v.y * v.y;
  #pragma unroll
  for (int m = 32; m > 0; m >>= 1) ss += __shfl_xor(ss, m);
  if (lane == 0) {
    rinv[row] = 1.0f / sqrtf(ss);
    deg[row]  = 1;          // self-loop
    wcnt[row] = 0;
  }
}

// ---------------------------------------------------- K2: M = X̂ᵀ X  (partials)
// 128 blocks; stage 64 rows (32 KB) ONCE, then barrier-free outer products.
// thread (ty,tx) in 16x16 owns an 8x8 tile of M; ds_read_b128 fragment loads.
__global__ __launch_bounds__(256) void k_xtx_partial(const float* __restrict__ x,
    const float* __restrict__ rinv, float* __restrict__ Mpart) {
  __shared__ float xs[64 * DIM];   // 32 KB
  __shared__ float rvs[64];
  int tid = threadIdx.x;
  int row0 = blockIdx.x * 64;
  const float4* xsrc = (const float4*)(x + (size_t)row0 * DIM);
  float4* xdst = (float4*)xs;
  #pragma unroll
  for (int i = 0; i < 8; ++i) xdst[tid + 256 * i] = xsrc[tid + 256 * i];
  if (tid < 64) rvs[tid] = rinv[row0 + tid];
  __syncthreads();

  int ty = tid >> 4, tx = tid & 15;
  float acc[8][8];
  #pragma unroll
  for (int i = 0; i < 8; ++i)
    #pragma unroll
    for (int j = 0; j < 8; ++j) acc[i][j] = 0.f;

  #pragma unroll 2
  for (int r = 0; r < 64; ++r) {
    float4 a0 = *(const float4*)&xs[r * DIM + ty * 8];
    float4 a1 = *(const float4*)&xs[r * DIM + ty * 8 + 4];
    float4 b0 = *(const float4*)&xs[r * DIM + tx * 8];
    float4 b1 = *(const float4*)&xs[r * DIM + tx * 8 + 4];
    float rv = rvs[r];
    float a[8] = {a0.x * rv, a0.y * rv, a0.z * rv, a0.w * rv,
                  a1.x * rv, a1.y * rv, a1.z * rv, a1.w * rv};
    float b[8] = {b0.x, b0.y, b0.z, b0.w, b1.x, b1.y, b1.z, b1.w};
    #pragma unroll
    for (int i = 0; i < 8; ++i)
      #pragma unroll
      for (int j = 0; j < 8; ++j) acc[i][j] += a[i] * b[j];
  }
  float* o = Mpart + (size_t)blockIdx.x * (DIM * DIM);
  #pragma unroll
  for (int i = 0; i < 8; ++i) {
    *(float4*)&o[(ty * 8 + i) * DIM + tx * 8]     = make_float4(acc[i][0], acc[i][1], acc[i][2], acc[i][3]);
    *(float4*)&o[(ty * 8 + i) * DIM + tx * 8 + 4] = make_float4(acc[i][4], acc[i][5], acc[i][6], acc[i][7]);
  }
}

__global__ void k_xtx_reduce(const float* __restrict__ Mpart, float* __restrict__ M) {
  int j = blockIdx.x * blockDim.x + threadIdx.x;   // 4096 threads x float4
  float4 s = {0.f, 0.f, 0.f, 0.f};
  for (int k = 0; k < XB; ++k) {
    float4 v = *(const float4*)&Mpart[(size_t)k * (DIM * DIM) + j * 4];
    s.x += v.x; s.y += v.y; s.z += v.z; s.w += v.w;
  }
  *(float4*)&M[j * 4] = s;
}

// ------------------------------------------------------------- K3: degree hist
__global__ void k_hist(const int* __restrict__ ei, int* __restrict__ deg) {
  int e4 = blockIdx.x * blockDim.x + threadIdx.x;
  int4 v = ((const int4*)(ei + NE))[e4];   // targets
  atomicAdd(&deg[v.x], 1);
  atomicAdd(&deg[v.y], 1);
  atomicAdd(&deg[v.z], 1);
  atomicAdd(&deg[v.w], 1);
}

// -------------------------------------------------- K4: scan (1 block) + dis
__global__ __launch_bounds__(1024) void k_scan(const int* __restrict__ deg,
    int* __restrict__ offs, float* __restrict__ dis) {
  __shared__ int sums[1024];
  int t = threadIdx.x;
  int base_i = t * 8;
  int local[8];
  int s = 0;
  #pragma unroll
  for (int j = 0; j < 8; ++j) { int v = deg[base_i + j] - 1; local[j] = s; s += v; }
  sums[t] = s;
  __syncthreads();
  for (int off = 1; off < 1024; off <<= 1) {
    int v = (t >= off) ? sums[t - off] : 0;
    __syncthreads();
    sums[t] += v;
    __syncthreads();
  }
  int b = (t > 0) ? sums[t - 1] : 0;
  #pragma unroll
  for (int j = 0; j < 8; ++j) {
    offs[base_i + j] = b + local[j];
    dis[base_i + j]  = 1.0f / sqrtf((float)deg[base_i + j]);   // deg >= 1 always
  }
}

// -------------------------------------------------- K5: counting-sort placement
__global__ void k_place(const int* __restrict__ ei, const int* __restrict__ offs,
    int* __restrict__ wcnt, int* __restrict__ sorted) {
  int e = blockIdx.x * blockDim.x + threadIdx.x;
  int c = ei[NE + e];
  int p = offs[c] + atomicAdd(&wcnt[c], 1);
  sorted[p] = ei[e];                 // source = edge_index[0]
}

// -------------------------------- K6: xw = X@W  and  att = sigmoid(rinv*(X@M))
// 512 blocks x 256 threads; 16 rows/block; thread = 2 rows x 4 cols x {W,M}.
// x-tile in LDS (8 KB); W/M rows streamed from L1/L2; NO inner barriers.
#define RWB 16
__global__ __launch_bounds__(256) void k_xw_att(const float* __restrict__ x,
    const float* __restrict__ W, const float* __restrict__ M,
    const float* __restrict__ rinv, float* __restrict__ xw, float* __restrict__ att) {
  __shared__ float xs[RWB * DIM];   // 8 KB
  __shared__ float rvs[RWB];
  int tid = threadIdx.x;
  int row0 = blockIdx.x * RWB;
  const float4* xsrc = (const float4*)(x + (size_t)row0 * DIM);
  float4* xdst = (float4*)xs;
  xdst[tid]       = xsrc[tid];
  xdst[tid + 256] = xsrc[tid + 256];
  if (tid < RWB) rvs[tid] = rinv[row0 + tid];
  __syncthreads();

  int ty = tid >> 5;                // 0..7  -> rows ty*2, ty*2+1
  int tx = tid & 31;                // cols tx*4
  int r0 = ty * 2, r1 = r0 + 1;
  float4 aw0 = {0,0,0,0}, aw1 = {0,0,0,0}, am0 = {0,0,0,0}, am1 = {0,0,0,0};
  const float* Wp = W + tx * 4;
  const float* Mp = M + tx * 4;

  #pragma unroll 4
  for (int k = 0; k < DIM; ++k) {
    float4 wv = *(const float4*)(Wp + k * DIM);
    float4 mv = *(const float4*)(Mp + k * DIM);
    float x0 = xs[r0 * DIM + k];
    float x1 = xs[r1 * DIM + k];
    aw0.x += x0 * wv.x; aw0.y += x0 * wv.y; aw0.z += x0 * wv.z; aw0.w += x0 * wv.w;
    aw1.x += x1 * wv.x; aw1.y += x1 * wv.y; aw1.z += x1 * wv.z; aw1.w += x1 * wv.w;
    am0.x += x0 * mv.x; am0.y += x0 * mv.y; am0.z += x0 * mv.z; am0.w += x0 * mv.w;
    am1.x += x1 * mv.x; am1.y += x1 * mv.y; am1.z += x1 * mv.z; am1.w += x1 * mv.w;
  }

  float rv0 = rvs[r0], rv1 = rvs[r1];
  size_t o0 = (size_t)(row0 + r0) * DIM + tx * 4;
  size_t o1 = (size_t)(row0 + r1) * DIM + tx * 4;
  *(float4*)&xw[o0] = aw0;
  *(float4*)&xw[o1] = aw1;
  float4 s0, s1;
  s0.x = 1.0f / (1.0f + __expf(-am0.x * rv0));
  s0.y = 1.0f / (1.0f + __expf(-am0.y * rv0));
  s0.z = 1.0f / (1.0f + __expf(-am0.z * rv0));
  s0.w = 1.0f / (1.0f + __expf(-am0.w * rv0));
  s1.x = 1.0f / (1.0f + __expf(-am1.x * rv1));
  s1.y = 1.0f / (1.0f + __expf(-am1.y * rv1));
  s1.z = 1.0f / (1.0f + __expf(-am1.z * rv1));
  s1.w = 1.0f / (1.0f + __expf(-am1.w * rv1));
  *(float4*)&att[o0] = s0;
  *(float4*)&att[o1] = s1;
}

// ---------------------------- K7: CSR gather + self-loop + bias + att-multiply
__global__ __launch_bounds__(128) void k_gather(const int* __restrict__ sorted,
    const int* __restrict__ offs, const int* __restrict__ deg,
    const float* __restrict__ dis, const float* __restrict__ xw,
    const float* __restrict__ att, const float* __restrict__ bias,
    float* __restrict__ out) {
  int c = blockIdx.x;
  int t = threadIdx.x;
  int base = offs[c];
  int cnt  = deg[c] - 1;
  float acc = 0.f;
  int k = 0;
  for (; k + 4 <= cnt; k += 4) {
    int s0 = sorted[base + k + 0];
    int s1 = sorted[base + k + 1];
    int s2 = sorted[base + k + 2];
    int s3 = sorted[base + k + 3];
    float d0 = dis[s0], d1 = dis[s1], d2 = dis[s2], d3 = dis[s3];
    acc += xw[(size_t)s0 * DIM + t] * d0;
    acc += xw[(size_t)s1 * DIM + t] * d1;
    acc += xw[(size_t)s2 * DIM + t] * d2;
    acc += xw[(size_t)s3 * DIM + t] * d3;
  }
  for (; k < cnt; ++k) {
    int s = sorted[base + k];
    acc += xw[(size_t)s * DIM + t] * dis[s];
  }
  float dc = dis[c];
  float g = acc * dc + xw[(size_t)c * DIM + t] * (dc * dc) + bias[t];
  out[(size_t)c * DIM + t] = g * att[(size_t)c * DIM + t];
}

// ---------------------------------------------------------------------- launch
extern "C" void kernel_launch(void* const* d_in, const int* in_sizes, int n_in,
                              void* d_out, int out_size, void* d_ws, size_t ws_size,
                              hipStream_t stream) {
  const float* x  = (const float*)d_in[0];   // [8192,128] f32
  const int*   ei = (const int*)  d_in[1];   // [2,262144] i32
  const float* W  = (const float*)d_in[2];   // [128,128] f32
  const float* b  = (const float*)d_in[3];   // [128] f32
  float* out = (float*)d_out;                // [8192,128] f32

  // ws layout (≈13.3 MB, identical to round 1):
  float* xw     = (float*)d_ws;                    // N*DIM
  float* Mpart  = xw + (size_t)NN * DIM;           // XB*DIM*DIM (8 MB)
  float* att    = Mpart;                           // overlays Mpart AFTER reduce
  float* M      = Mpart + (size_t)XB * DIM * DIM;  // DIM*DIM
  float* rinv   = M + DIM * DIM;                   // N
  float* dis    = rinv + NN;                       // N
  int*   deg    = (int*)(dis + NN);                // N
  int*   wcnt   = deg + NN;                        // N
  int*   offs   = wcnt + NN;                       // N
  int*   sorted = offs + NN;                       // E

  k_row_prep   <<<NN / 4, 256, 0, stream>>>(x, rinv, deg, wcnt);
  k_xtx_partial<<<XB, 256, 0, stream>>>(x, rinv, Mpart);
  k_xtx_reduce <<<DIM * DIM / 4 / 256, 256, 0, stream>>>(Mpart, M);
  k_hist       <<<NE / 4 / 256, 256, 0, stream>>>(ei, deg);
  k_scan       <<<1, 1024, 0, stream>>>(deg, offs, dis);
  k_place      <<<NE / 256, 256, 0, stream>>>(ei, offs, wcnt, sorted);
  k_xw_att     <<<NN / RWB, 256, 0, stream>>>(x, W, M, rinv, xw, att);
  k_gather     <<<NN, 128, 0, stream>>>(sorted, offs, deg, dis, xw, att, b, out);
}